// Round 5
// baseline (440.360 us; speedup 1.0000x reference)
//
#include <hip/hip_runtime.h>

typedef __bf16 bf16;
typedef __bf16 bf16x8 __attribute__((ext_vector_type(8)));
typedef float f32x4 __attribute__((ext_vector_type(4)));

#define MFMA16(a, b, c) __builtin_amdgcn_mfma_f32_16x16x32_bf16(a, b, c, 0, 0, 0)

static constexpr int Bn = 8;
static constexpr int Tn = 1024;
static constexpr int Cn = 1024;
static constexpr int Hn = 16;

typedef const __attribute__((address_space(1))) unsigned int* gp_t;
typedef __attribute__((address_space(3))) unsigned int* lp_t;
__device__ __forceinline__ void gload_lds16(const bf16* g, bf16* l) {
    __builtin_amdgcn_global_load_lds((gp_t)(const void*)g, (lp_t)(void*)l, 16, 0, 0);
}

// ---------------------------------------------------------------------------
// Merged transpose+cast: all four weights fp32 [K][N] -> bf16 [N][K], 1 dispatch
// ---------------------------------------------------------------------------
__global__ __launch_bounds__(256) void tcast_all(const float* __restrict__ Wqkv,
                                                 const float* __restrict__ Wproj,
                                                 const float* __restrict__ W1,
                                                 const float* __restrict__ W2,
                                                 bf16* __restrict__ WqkvT,
                                                 bf16* __restrict__ WprojT,
                                                 bf16* __restrict__ W1T,
                                                 bf16* __restrict__ W2T) {
    int bid = blockIdx.x;
    const float* in;
    bf16* out;
    int K, N;
    if (bid < 3072) {
        in = Wqkv; out = WqkvT; K = 1024; N = 3072;
    } else if (bid < 4096) {
        bid -= 3072; in = Wproj; out = WprojT; K = 1024; N = 1024;
    } else if (bid < 8192) {
        bid -= 4096; in = W1; out = W1T; K = 1024; N = 4096;
    } else {
        bid -= 8192; in = W2; out = W2T; K = 4096; N = 1024;
    }
    const int ntx = N / 32;
    const int n0 = (bid % ntx) * 32, k0 = (bid / ntx) * 32;
    __shared__ float tile[32][33];
    const int tx = threadIdx.x & 31, ty = threadIdx.x >> 5;  // 32 x 8
#pragma unroll
    for (int i = 0; i < 4; i++)
        tile[ty + 8 * i][tx] = in[(size_t)(k0 + ty + 8 * i) * N + n0 + tx];
    __syncthreads();
#pragma unroll
    for (int i = 0; i < 4; i++)
        out[(size_t)(n0 + ty + 8 * i) * K + k0 + tx] = (bf16)tile[tx][ty + 8 * i];
}

// ---------------------------------------------------------------------------
// LayerNorm row (fp32 or bf16 input) -> bf16 row. One block per row, C=1024.
// ---------------------------------------------------------------------------
template <typename T>
__global__ __launch_bounds__(256) void ln_row(const T* __restrict__ x,
                                              const float* __restrict__ g,
                                              const float* __restrict__ be,
                                              bf16* __restrict__ out) {
    const int row = blockIdx.x, t = threadIdx.x;
    const T* xr = x + (size_t)row * Cn;
    float v[4], s = 0.f, s2 = 0.f;
#pragma unroll
    for (int i = 0; i < 4; i++) {
        v[i] = (float)xr[t + i * 256];
        s += v[i];
        s2 += v[i] * v[i];
    }
#pragma unroll
    for (int off = 32; off > 0; off >>= 1) {
        s += __shfl_down(s, off);
        s2 += __shfl_down(s2, off);
    }
    __shared__ float red[8];
    const int wave = t >> 6, lane = t & 63;
    if (lane == 0) {
        red[wave] = s;
        red[4 + wave] = s2;
    }
    __syncthreads();
    s = red[0] + red[1] + red[2] + red[3];
    s2 = red[4] + red[5] + red[6] + red[7];
    const float mu = s * (1.f / Cn);
    const float rstd = rsqrtf(s2 * (1.f / Cn) - mu * mu + 1e-5f);
    bf16* orow = out + (size_t)row * Cn;
#pragma unroll
    for (int i = 0; i < 4; i++) {
        int c = t + i * 256;
        orow[c] = (bf16)((v[i] - mu) * rstd * g[c] + be[c]);
    }
}

// ---------------------------------------------------------------------------
// V transpose: qkv v-part [B,T,H,64] -> Vt [B,H,64,T]
// ---------------------------------------------------------------------------
__global__ __launch_bounds__(256) void vtrans(const bf16* __restrict__ qkv,
                                              bf16* __restrict__ Vt) {
    __shared__ bf16 tile[64 * 72];
    const int tid = threadIdx.x;
    const int bh = blockIdx.x, b = bh >> 4, h = bh & 15;
    const int t0 = blockIdx.y * 64;
    const int r = tid >> 3, c = (tid & 7) * 8;
#pragma unroll
    for (int i = 0; i < 2; i++) {
        const int rr = r + i * 32;
        *(bf16x8*)(tile + rr * 72 + c) =
            *(const bf16x8*)(qkv + ((size_t)(b * Tn + t0 + rr)) * 3072 + 2 * Cn + h * 64 + c);
    }
    __syncthreads();
#pragma unroll
    for (int i = 0; i < 2; i++) {
        const int d = r + i * 32;
        bf16x8 v;
#pragma unroll
        for (int j = 0; j < 8; j++) v[j] = tile[(c + j) * 72 + d];
        *(bf16x8*)(Vt + ((size_t)bh * 64 + d) * Tn + t0 + c) = v;
    }
}

// ---------------------------------------------------------------------------
// GEMM: out[M,N] = A[M,K] @ Bt[N,K]^T + bias (+ relu) (+ resid)
// TMxTN tile, BK in {64,128}, 4 waves (2x2), wave tile (TM/2)x(TN/2).
// global_load_lds w16 staging, XOR-swizzled LDS (16B chunk c of row r at
// phys chunk c^(r&7)) -> conflict-free ds_read_b128.
// ---------------------------------------------------------------------------
template <int TM, int TN, int BK, bool RELU, bool RESID, bool OUTBF16, typename RT>
__global__ __launch_bounds__(256, 2) void gemm_bt(const bf16* __restrict__ A,
                                                  const bf16* __restrict__ Bt,
                                                  const float* __restrict__ bias,
                                                  const RT* __restrict__ resid,
                                                  void* __restrict__ outp,
                                                  int M, int N, int K) {
    constexpr int MI = TM / 32;        // m 16-tiles per wave
    constexpr int NI = TN / 32;        // n 16-tiles per wave
    constexpr int CPR = BK / 8;        // 16B chunks per LDS row
    constexpr int RPG = 64 / CPR;      // rows covered per gload
    constexpr int AJ = TM / (4 * RPG); // A gloads per wave
    constexpr int BJ = TN / (4 * RPG); // B gloads per wave
    __shared__ __align__(16) bf16 As[TM * BK];
    __shared__ __align__(16) bf16 Bs[TN * BK];
    const int t = threadIdx.x;
    const int lane = t & 63, wave = t >> 6;
    const int lane15 = lane & 15, quad = lane >> 4;
    const int m0 = blockIdx.x * TM, n0 = blockIdx.y * TN;
    const int mb = (wave >> 1) * (TM / 2), nb = (wave & 1) * (TN / 2);

    const f32x4 zero4 = {0.f, 0.f, 0.f, 0.f};
    f32x4 acc[MI][NI];
#pragma unroll
    for (int i = 0; i < MI; i++)
#pragma unroll
        for (int j = 0; j < NI; j++) acc[i][j] = zero4;

    const int grow = lane / CPR;
    const int gsub = lane % CPR;

    for (int kt = 0; kt < K; kt += BK) {
#pragma unroll
        for (int j = 0; j < AJ; j++) {
            const int rj = wave * (AJ * RPG) + j * RPG + grow;
            const int cj = (gsub ^ (rj & 7)) * 8;
            gload_lds16(A + (size_t)(m0 + rj) * K + kt + cj,
                        As + (wave * (AJ * RPG) + j * RPG) * BK);
        }
#pragma unroll
        for (int j = 0; j < BJ; j++) {
            const int rj = wave * (BJ * RPG) + j * RPG + grow;
            const int cj = (gsub ^ (rj & 7)) * 8;
            gload_lds16(Bt + (size_t)(n0 + rj) * K + kt + cj,
                        Bs + (wave * (BJ * RPG) + j * RPG) * BK);
        }
        __syncthreads();
#pragma unroll
        for (int kk = 0; kk < BK / 32; kk++) {
            bf16x8 fa[MI], fb[NI];
#pragma unroll
            for (int mi = 0; mi < MI; mi++) {
                const int r = mb + mi * 16 + lane15;
                fa[mi] = *(const bf16x8*)(As + r * BK + (((kk * 4 + quad) ^ (r & 7)) * 8));
            }
#pragma unroll
            for (int ni = 0; ni < NI; ni++) {
                const int r = nb + ni * 16 + lane15;
                fb[ni] = *(const bf16x8*)(Bs + r * BK + (((kk * 4 + quad) ^ (r & 7)) * 8));
            }
#pragma unroll
            for (int mi = 0; mi < MI; mi++)
#pragma unroll
                for (int ni = 0; ni < NI; ni++)
                    acc[mi][ni] = MFMA16(fa[mi], fb[ni], acc[mi][ni]);
        }
        __syncthreads();
    }

    float bsv[NI];
#pragma unroll
    for (int ni = 0; ni < NI; ni++) bsv[ni] = bias[n0 + nb + ni * 16 + lane15];
#pragma unroll
    for (int mi = 0; mi < MI; mi++) {
#pragma unroll
        for (int reg = 0; reg < 4; reg++) {
            const int row = m0 + mb + mi * 16 + quad * 4 + reg;
#pragma unroll
            for (int ni = 0; ni < NI; ni++) {
                const int col = n0 + nb + ni * 16 + lane15;
                float v = acc[mi][ni][reg] + bsv[ni];
                if (RELU) v = v > 0.f ? v : 0.f;
                if (RESID) v += (float)resid[(size_t)row * N + col];
                if (OUTBF16)
                    ((bf16*)outp)[(size_t)row * N + col] = (bf16)v;
                else
                    ((float*)outp)[(size_t)row * N + col] = v;
            }
        }
    }
}

// ---------------------------------------------------------------------------
// Flash attention, causal. Q-tile 128 rows/block (32/wave), K-block 64.
// global_load_lds staging + XOR swizzle + K/V double-buffer (1 barrier/iter).
// No max-tracking (bounded logits); row-sum via ones-row MFMA.
// ---------------------------------------------------------------------------
__global__ __launch_bounds__(256) void attn(const bf16* __restrict__ qkv,
                                            const bf16* __restrict__ Vt,
                                            bf16* __restrict__ y) {
    __shared__ __align__(16) bf16 Ks[2][64 * 64];   // [key][d], swizzled
    __shared__ __align__(16) bf16 Vs[2][64 * 64];   // [d][key], swizzled
    __shared__ __align__(16) bf16 Ones[16 * 64];    // row 0 = ones, rest 0
    __shared__ __align__(16) bf16 Ps[4][32 * 64];   // per-wave P, swizzled
    const int tid = threadIdx.x, lane = tid & 63, wave = tid >> 6;
    const int lane15 = lane & 15, quad = lane >> 4;
    const int b = blockIdx.x >> 4, h = blockIdx.x & 15;
    const int q0 = blockIdx.y * 128;
    const int qr0 = q0 + wave * 32;
    const float c1 = 0.10412043f;  // (1/sqrt(192)) * log2(e)

    for (int i = tid; i < 16 * 64; i += 256) Ones[i] = (bf16)((i < 64) ? 1.0f : 0.0f);

    // staging geometry: per wave 2 gloads each for K and V; gload j covers
    // rows wave*16 + j*8 + (lane>>3); swizzled source chunk (lane&7)^(lane>>3)
    const int grow = lane >> 3;
    const int gcol = ((lane & 7) ^ grow) * 8;
    const int srow = wave * 16 + grow;
    const bf16* gK = qkv + ((size_t)(b * Tn + srow)) * 3072 + Cn + h * 64 + gcol;
    const bf16* gV = Vt + ((size_t)(blockIdx.x * 64 + srow)) * Tn + gcol;

    auto stage = [&](int kb, int p) {
        const int k0 = kb * 64;
#pragma unroll
        for (int j = 0; j < 2; j++) {
            gload_lds16(gK + (size_t)(k0 + j * 8) * 3072, &Ks[p][(wave * 16 + j * 8) * 64]);
            gload_lds16(gV + (size_t)(j * 8) * Tn + k0, &Vs[p][(wave * 16 + j * 8) * 64]);
        }
    };

    bf16x8 fq[2][2];
#pragma unroll
    for (int mi = 0; mi < 2; mi++) {
        const size_t qb = ((size_t)(b * Tn + qr0 + mi * 16 + lane15)) * 3072 + h * 64;
#pragma unroll
        for (int kk = 0; kk < 2; kk++)
            fq[mi][kk] = *(const bf16x8*)(qkv + qb + kk * 32 + quad * 8);
    }

    const f32x4 zero4 = {0.f, 0.f, 0.f, 0.f};
    f32x4 o[2][4], lacc[2];
#pragma unroll
    for (int mi = 0; mi < 2; mi++) {
        lacc[mi] = zero4;
#pragma unroll
        for (int ni = 0; ni < 4; ni++) o[mi][ni] = zero4;
    }

    stage(0, 0);
    const int nkb = q0 / 64 + 2;
    for (int kb = 0; kb < nkb; kb++) {
        const int p = kb & 1;
        const int k0 = kb * 64;
        __syncthreads();  // stage(kb) landed; compute(kb-1) done with buf 1-p
        if (kb + 1 < nkb) stage(kb + 1, 1 - p);

        if (k0 <= qr0 + 31) {
            bf16x8 fk[4][2];
#pragma unroll
            for (int ni = 0; ni < 4; ni++) {
                const int r = ni * 16 + lane15;
#pragma unroll
                for (int kk = 0; kk < 2; kk++)
                    fk[ni][kk] = *(const bf16x8*)(&Ks[p][r * 64 + (((kk * 4 + quad) ^ (r & 7)) * 8)]);
            }
            f32x4 s[2][4];
#pragma unroll
            for (int mi = 0; mi < 2; mi++)
#pragma unroll
                for (int ni = 0; ni < 4; ni++) {
                    if (k0 + ni * 16 <= qr0 + mi * 16 + 15) {  // tile not fully masked
                        f32x4 a = zero4;
                        a = MFMA16(fq[mi][0], fk[ni][0], a);
                        a = MFMA16(fq[mi][1], fk[ni][1], a);
                        s[mi][ni] = a;
                    }
                }
            // p = exp2(s*c1) (+ causal), store swizzled into Ps[wave]
            const bool domask = (k0 + 63 > qr0);
#pragma unroll
            for (int mi = 0; mi < 2; mi++)
#pragma unroll
                for (int ni = 0; ni < 4; ni++) {
#pragma unroll
                    for (int r = 0; r < 4; r++) {
                        const int prow = mi * 16 + quad * 4 + r;
                        const int r7 = (quad * 4 + r) & 7;
                        const int paddr = prow * 64 + (((ni * 2 + (lane15 >> 3)) ^ r7) * 8) +
                                          (lane15 & 7);
                        float val;
                        if (domask && (k0 + ni * 16 > qr0 + mi * 16 + 15)) {
                            val = 0.f;  // fully masked tile
                        } else if (domask && (k0 + ni * 16 + 15 > qr0 + mi * 16)) {
                            const int key = k0 + ni * 16 + lane15;
                            const int row = qr0 + prow;
                            float L = (key > row) ? -1e30f : s[mi][ni][r] * c1;
                            val = __builtin_amdgcn_exp2f(L);
                        } else {
                            val = __builtin_amdgcn_exp2f(s[mi][ni][r] * c1);
                        }
                        Ps[wave][paddr] = (bf16)val;
                    }
                }
            bf16x8 fp[2][2];
#pragma unroll
            for (int mi = 0; mi < 2; mi++) {
                const int r = mi * 16 + lane15;
#pragma unroll
                for (int kk = 0; kk < 2; kk++)
                    fp[mi][kk] = *(const bf16x8*)(&Ps[wave][r * 64 + (((kk * 4 + quad) ^ (r & 7)) * 8)]);
            }
            const bool use_kk1 = (k0 + 32 <= qr0 + 31);
#pragma unroll
            for (int ni = 0; ni < 5; ni++) {
                bf16x8 fv0, fv1;
                if (ni < 4) {
                    const int r = ni * 16 + lane15;
                    fv0 = *(const bf16x8*)(&Vs[p][r * 64 + ((quad ^ (r & 7)) * 8)]);
                    fv1 = *(const bf16x8*)(&Vs[p][r * 64 + (((4 + quad) ^ (r & 7)) * 8)]);
                } else {
                    fv0 = *(const bf16x8*)(Ones + lane15 * 64 + quad * 8);
                    fv1 = *(const bf16x8*)(Ones + lane15 * 64 + 32 + quad * 8);
                }
#pragma unroll
                for (int mi = 0; mi < 2; mi++) {
                    f32x4* dst = (ni < 4) ? &o[mi][ni] : &lacc[mi];
                    f32x4 a = *dst;
                    a = MFMA16(fp[mi][0], fv0, a);
                    if (use_kk1) a = MFMA16(fp[mi][1], fv1, a);
                    *dst = a;
                }
            }
        }
    }

#pragma unroll
    for (int mi = 0; mi < 2; mi++)
#pragma unroll
        for (int r = 0; r < 4; r++) {
            float l = __shfl(lacc[mi][r], lane & 48);
            const float inv = 1.f / l;
            const size_t base = ((size_t)(b * Tn + qr0 + mi * 16 + quad * 4 + r)) * Cn + h * 64;
#pragma unroll
            for (int ni = 0; ni < 4; ni++)
                y[base + ni * 16 + lane15] = (bf16)(o[mi][ni][r] * inv);
        }
}

// ---------------------------------------------------------------------------
extern "C" void kernel_launch(void* const* d_in, const int* in_sizes, int n_in,
                              void* d_out, int out_size, void* d_ws, size_t ws_size,
                              hipStream_t stream) {
    const float* x = (const float*)d_in[0];
    const float* Wqkv = (const float*)d_in[1];
    const float* bqkv = (const float*)d_in[2];
    const float* Wproj = (const float*)d_in[3];
    const float* bproj = (const float*)d_in[4];
    const float* ln1g = (const float*)d_in[5];
    const float* ln1b = (const float*)d_in[6];
    const float* ln2g = (const float*)d_in[7];
    const float* ln2b = (const float*)d_in[8];
    const float* W1 = (const float*)d_in[9];
    const float* b1 = (const float*)d_in[10];
    const float* W2 = (const float*)d_in[11];
    const float* b2 = (const float*)d_in[12];
    float* out = (float*)d_out;

    char* ws = (char*)d_ws;
    size_t off = 0;
    auto alloc = [&](size_t bytes) {
        void* p = ws + off;
        off += (bytes + 255) & ~(size_t)255;
        return p;
    };
    bf16* WqkvT = (bf16*)alloc((size_t)3072 * 1024 * 2);
    bf16* WprojT = (bf16*)alloc((size_t)1024 * 1024 * 2);
    bf16* W1T = (bf16*)alloc((size_t)4096 * 1024 * 2);
    bf16* W2T = (bf16*)alloc((size_t)1024 * 4096 * 2);
    bf16* hbuf = (bf16*)alloc((size_t)8192 * 1024 * 2);
    bf16* qkvb = (bf16*)alloc((size_t)8192 * 3072 * 2);
    bf16* ybuf = (bf16*)alloc((size_t)8192 * 1024 * 2);
    bf16* vtb = (bf16*)alloc((size_t)8192 * 1024 * 2);
    bf16* x1b = (bf16*)alloc((size_t)8192 * 1024 * 2);
    bf16* a1 = qkvb;  // reuse qkv(48MB)+y(16MB) region for a1 (64MB); dead by MLP1

    // all weights -> bf16 transposed, single dispatch
    tcast_all<<<12288, 256, 0, stream>>>(Wqkv, Wproj, W1, W2, WqkvT, WprojT, W1T, W2T);

    // LN1 -> h
    ln_row<float><<<8192, 256, 0, stream>>>(x, ln1g, ln1b, hbuf);
    // qkv = h @ Wqkv + bqkv  (bf16)   TM=128, TN=256, BK=64
    gemm_bt<128, 256, 64, false, false, true, float><<<dim3(64, 12), 256, 0, stream>>>(
        hbuf, WqkvT, bqkv, (const float*)nullptr, qkvb, 8192, 3072, 1024);
    // V -> Vt [B,H,64,T]
    vtrans<<<dim3(Bn * Hn, Tn / 64), 256, 0, stream>>>(qkvb, vtb);
    // attention -> y (bf16)
    attn<<<dim3(Bn * Hn, Tn / 128), 256, 0, stream>>>(qkvb, vtb, ybuf);
    // x1 = x + y @ Wproj + bproj  (bf16)   TM=TN=128, BK=128 (grid-limited 2 blk/CU)
    gemm_bt<128, 128, 128, false, true, true, float><<<dim3(64, 8), 256, 0, stream>>>(
        ybuf, WprojT, bproj, x, x1b, 8192, 1024, 1024);
    // LN2 -> h
    ln_row<bf16><<<8192, 256, 0, stream>>>(x1b, ln2g, ln2b, hbuf);
    // a1 = relu(h @ W1 + b1)  (bf16)   TM=128, TN=256, BK=64
    gemm_bt<128, 256, 64, true, false, true, float><<<dim3(64, 16), 256, 0, stream>>>(
        hbuf, W1T, b1, (const float*)nullptr, a1, 8192, 4096, 1024);
    // out = x1 + a1 @ W2 + b2  (fp32)   TM=TN=128, BK=128
    gemm_bt<128, 128, 128, false, true, false, bf16><<<dim3(64, 8), 256, 0, stream>>>(
        a1, W2T, b2, x1b, out, 8192, 1024, 4096);
}

// Round 6
// 432.591 us; speedup vs baseline: 1.0180x; 1.0180x over previous
//
#include <hip/hip_runtime.h>

typedef __bf16 bf16;
typedef __bf16 bf16x8 __attribute__((ext_vector_type(8)));
typedef float f32x4 __attribute__((ext_vector_type(4)));

#define MFMA16(a, b, c) __builtin_amdgcn_mfma_f32_16x16x32_bf16(a, b, c, 0, 0, 0)

static constexpr int Bn = 8;
static constexpr int Tn = 1024;
static constexpr int Cn = 1024;
static constexpr int Hn = 16;

typedef const __attribute__((address_space(1))) unsigned int* gp_t;
typedef __attribute__((address_space(3))) unsigned int* lp_t;
__device__ __forceinline__ void gload_lds16(const bf16* g, bf16* l) {
    __builtin_amdgcn_global_load_lds((gp_t)(const void*)g, (lp_t)(void*)l, 16, 0, 0);
}

// ---------------------------------------------------------------------------
// Merged transpose+cast: all four weights fp32 [K][N] -> bf16 [N][K], 1 dispatch
// ---------------------------------------------------------------------------
__global__ __launch_bounds__(256) void tcast_all(const float* __restrict__ Wqkv,
                                                 const float* __restrict__ Wproj,
                                                 const float* __restrict__ W1,
                                                 const float* __restrict__ W2,
                                                 bf16* __restrict__ WqkvT,
                                                 bf16* __restrict__ WprojT,
                                                 bf16* __restrict__ W1T,
                                                 bf16* __restrict__ W2T) {
    int bid = blockIdx.x;
    const float* in;
    bf16* out;
    int K, N;
    if (bid < 3072) {
        in = Wqkv; out = WqkvT; K = 1024; N = 3072;
    } else if (bid < 4096) {
        bid -= 3072; in = Wproj; out = WprojT; K = 1024; N = 1024;
    } else if (bid < 8192) {
        bid -= 4096; in = W1; out = W1T; K = 1024; N = 4096;
    } else {
        bid -= 8192; in = W2; out = W2T; K = 4096; N = 1024;
    }
    const int ntx = N / 32;
    const int n0 = (bid % ntx) * 32, k0 = (bid / ntx) * 32;
    __shared__ float tile[32][33];
    const int tx = threadIdx.x & 31, ty = threadIdx.x >> 5;  // 32 x 8
#pragma unroll
    for (int i = 0; i < 4; i++)
        tile[ty + 8 * i][tx] = in[(size_t)(k0 + ty + 8 * i) * N + n0 + tx];
    __syncthreads();
#pragma unroll
    for (int i = 0; i < 4; i++)
        out[(size_t)(n0 + ty + 8 * i) * K + k0 + tx] = (bf16)tile[tx][ty + 8 * i];
}

// ---------------------------------------------------------------------------
// LayerNorm row (fp32 or bf16 input) -> bf16 row. One block per row, C=1024.
// ---------------------------------------------------------------------------
template <typename T>
__global__ __launch_bounds__(256) void ln_row(const T* __restrict__ x,
                                              const float* __restrict__ g,
                                              const float* __restrict__ be,
                                              bf16* __restrict__ out) {
    const int row = blockIdx.x, t = threadIdx.x;
    const T* xr = x + (size_t)row * Cn;
    float v[4], s = 0.f, s2 = 0.f;
#pragma unroll
    for (int i = 0; i < 4; i++) {
        v[i] = (float)xr[t + i * 256];
        s += v[i];
        s2 += v[i] * v[i];
    }
#pragma unroll
    for (int off = 32; off > 0; off >>= 1) {
        s += __shfl_down(s, off);
        s2 += __shfl_down(s2, off);
    }
    __shared__ float red[8];
    const int wave = t >> 6, lane = t & 63;
    if (lane == 0) {
        red[wave] = s;
        red[4 + wave] = s2;
    }
    __syncthreads();
    s = red[0] + red[1] + red[2] + red[3];
    s2 = red[4] + red[5] + red[6] + red[7];
    const float mu = s * (1.f / Cn);
    const float rstd = rsqrtf(s2 * (1.f / Cn) - mu * mu + 1e-5f);
    bf16* orow = out + (size_t)row * Cn;
#pragma unroll
    for (int i = 0; i < 4; i++) {
        int c = t + i * 256;
        orow[c] = (bf16)((v[i] - mu) * rstd * g[c] + be[c]);
    }
}

// ---------------------------------------------------------------------------
// V transpose: qkv v-part [B,T,H,64] -> Vt [B,H,64,T]
// ---------------------------------------------------------------------------
__global__ __launch_bounds__(256) void vtrans(const bf16* __restrict__ qkv,
                                              bf16* __restrict__ Vt) {
    __shared__ bf16 tile[64 * 72];
    const int tid = threadIdx.x;
    const int bh = blockIdx.x, b = bh >> 4, h = bh & 15;
    const int t0 = blockIdx.y * 64;
    const int r = tid >> 3, c = (tid & 7) * 8;
#pragma unroll
    for (int i = 0; i < 2; i++) {
        const int rr = r + i * 32;
        *(bf16x8*)(tile + rr * 72 + c) =
            *(const bf16x8*)(qkv + ((size_t)(b * Tn + t0 + rr)) * 3072 + 2 * Cn + h * 64 + c);
    }
    __syncthreads();
#pragma unroll
    for (int i = 0; i < 2; i++) {
        const int d = r + i * 32;
        bf16x8 v;
#pragma unroll
        for (int j = 0; j < 8; j++) v[j] = tile[(c + j) * 72 + d];
        *(bf16x8*)(Vt + ((size_t)bh * 64 + d) * Tn + t0 + c) = v;
    }
}

// ---------------------------------------------------------------------------
// GEMM: out[M,N] = A[M,K] @ Bt[N,K]^T + bias (+ relu) (+ resid)
// TMxTN tile, BK in {64,128}, 4 waves (2x2), wave tile (TM/2)x(TN/2).
// global_load_lds w16 staging, XOR-swizzled LDS (16B chunk c of row r at
// phys chunk c^(r&7)) -> conflict-free ds_read_b128.
// ---------------------------------------------------------------------------
template <int TM, int TN, int BK, bool RELU, bool RESID, bool OUTBF16, typename RT>
__global__ __launch_bounds__(256, 2) void gemm_bt(const bf16* __restrict__ A,
                                                  const bf16* __restrict__ Bt,
                                                  const float* __restrict__ bias,
                                                  const RT* __restrict__ resid,
                                                  void* __restrict__ outp,
                                                  int M, int N, int K) {
    constexpr int MI = TM / 32;        // m 16-tiles per wave
    constexpr int NI = TN / 32;        // n 16-tiles per wave
    constexpr int CPR = BK / 8;        // 16B chunks per LDS row
    constexpr int RPG = 64 / CPR;      // rows covered per gload
    constexpr int AJ = TM / (4 * RPG); // A gloads per wave
    constexpr int BJ = TN / (4 * RPG); // B gloads per wave
    __shared__ __align__(16) bf16 As[TM * BK];
    __shared__ __align__(16) bf16 Bs[TN * BK];
    const int t = threadIdx.x;
    const int lane = t & 63, wave = t >> 6;
    const int lane15 = lane & 15, quad = lane >> 4;
    const int m0 = blockIdx.x * TM, n0 = blockIdx.y * TN;
    const int mb = (wave >> 1) * (TM / 2), nb = (wave & 1) * (TN / 2);

    const f32x4 zero4 = {0.f, 0.f, 0.f, 0.f};
    f32x4 acc[MI][NI];
#pragma unroll
    for (int i = 0; i < MI; i++)
#pragma unroll
        for (int j = 0; j < NI; j++) acc[i][j] = zero4;

    const int grow = lane / CPR;
    const int gsub = lane % CPR;

    for (int kt = 0; kt < K; kt += BK) {
#pragma unroll
        for (int j = 0; j < AJ; j++) {
            const int rj = wave * (AJ * RPG) + j * RPG + grow;
            const int cj = (gsub ^ (rj & 7)) * 8;
            gload_lds16(A + (size_t)(m0 + rj) * K + kt + cj,
                        As + (wave * (AJ * RPG) + j * RPG) * BK);
        }
#pragma unroll
        for (int j = 0; j < BJ; j++) {
            const int rj = wave * (BJ * RPG) + j * RPG + grow;
            const int cj = (gsub ^ (rj & 7)) * 8;
            gload_lds16(Bt + (size_t)(n0 + rj) * K + kt + cj,
                        Bs + (wave * (BJ * RPG) + j * RPG) * BK);
        }
        __syncthreads();
#pragma unroll
        for (int kk = 0; kk < BK / 32; kk++) {
            bf16x8 fa[MI], fb[NI];
#pragma unroll
            for (int mi = 0; mi < MI; mi++) {
                const int r = mb + mi * 16 + lane15;
                fa[mi] = *(const bf16x8*)(As + r * BK + (((kk * 4 + quad) ^ (r & 7)) * 8));
            }
#pragma unroll
            for (int ni = 0; ni < NI; ni++) {
                const int r = nb + ni * 16 + lane15;
                fb[ni] = *(const bf16x8*)(Bs + r * BK + (((kk * 4 + quad) ^ (r & 7)) * 8));
            }
#pragma unroll
            for (int mi = 0; mi < MI; mi++)
#pragma unroll
                for (int ni = 0; ni < NI; ni++)
                    acc[mi][ni] = MFMA16(fa[mi], fb[ni], acc[mi][ni]);
        }
        __syncthreads();
    }

    float bsv[NI];
#pragma unroll
    for (int ni = 0; ni < NI; ni++) bsv[ni] = bias[n0 + nb + ni * 16 + lane15];
#pragma unroll
    for (int mi = 0; mi < MI; mi++) {
#pragma unroll
        for (int reg = 0; reg < 4; reg++) {
            const int row = m0 + mb + mi * 16 + quad * 4 + reg;
#pragma unroll
            for (int ni = 0; ni < NI; ni++) {
                const int col = n0 + nb + ni * 16 + lane15;
                float v = acc[mi][ni][reg] + bsv[ni];
                if (RELU) v = v > 0.f ? v : 0.f;
                if (RESID) v += (float)resid[(size_t)row * N + col];
                if (OUTBF16)
                    ((bf16*)outp)[(size_t)row * N + col] = (bf16)v;
                else
                    ((float*)outp)[(size_t)row * N + col] = v;
            }
        }
    }
}

// ---------------------------------------------------------------------------
// Flash attention, causal, LOAD-BALANCED: block handles Q-tile pair (j, 7-j)
// -> uniform 18 K-iterations per block. Q-tile 128 rows, K-block 64.
// global_load_lds staging + XOR swizzle + K/V double-buffer.
// No max-tracking (bounded logits); row-sum via ones-row MFMA.
// ---------------------------------------------------------------------------
__global__ __launch_bounds__(256) void attn(const bf16* __restrict__ qkv,
                                            const bf16* __restrict__ Vt,
                                            bf16* __restrict__ y) {
    __shared__ __align__(16) bf16 Ks[2][64 * 64];   // [key][d], swizzled
    __shared__ __align__(16) bf16 Vs[2][64 * 64];   // [d][key], swizzled
    __shared__ __align__(16) bf16 Ones[16 * 64];    // row 0 = ones, rest 0
    __shared__ __align__(16) bf16 Ps[4][32 * 64];   // per-wave P, swizzled
    const int tid = threadIdx.x, lane = tid & 63, wave = tid >> 6;
    const int lane15 = lane & 15, quad = lane >> 4;
    const int b = blockIdx.x >> 4, h = blockIdx.x & 15;
    const float c1 = 0.10412043f;  // (1/sqrt(192)) * log2(e)

    for (int i = tid; i < 16 * 64; i += 256) Ones[i] = (bf16)((i < 64) ? 1.0f : 0.0f);

    const int grow = lane >> 3;
    const int gcol = ((lane & 7) ^ grow) * 8;
    const int srow = wave * 16 + grow;
    const bf16* gK = qkv + ((size_t)(b * Tn + srow)) * 3072 + Cn + h * 64 + gcol;
    const bf16* gV = Vt + ((size_t)(blockIdx.x * 64 + srow)) * Tn + gcol;

    auto stage = [&](int kb, int p) {
        const int k0 = kb * 64;
#pragma unroll
        for (int j = 0; j < 2; j++) {
            gload_lds16(gK + (size_t)(k0 + j * 8) * 3072, &Ks[p][(wave * 16 + j * 8) * 64]);
            gload_lds16(gV + (size_t)(j * 8) * Tn + k0, &Vs[p][(wave * 16 + j * 8) * 64]);
        }
    };

    const f32x4 zero4 = {0.f, 0.f, 0.f, 0.f};

#pragma unroll
    for (int half = 0; half < 2; half++) {
        const int qt = half == 0 ? (int)blockIdx.y : 7 - (int)blockIdx.y;
        const int q0 = qt * 128;
        const int qr0 = q0 + wave * 32;

        bf16x8 fq[2][2];
#pragma unroll
        for (int mi = 0; mi < 2; mi++) {
            const size_t qb = ((size_t)(b * Tn + qr0 + mi * 16 + lane15)) * 3072 + h * 64;
#pragma unroll
            for (int kk = 0; kk < 2; kk++)
                fq[mi][kk] = *(const bf16x8*)(qkv + qb + kk * 32 + quad * 8);
        }

        f32x4 o[2][4], lacc[2];
#pragma unroll
        for (int mi = 0; mi < 2; mi++) {
            lacc[mi] = zero4;
#pragma unroll
            for (int ni = 0; ni < 4; ni++) o[mi][ni] = zero4;
        }

        stage(0, 0);
        const int nkb = q0 / 64 + 2;
        for (int kb = 0; kb < nkb; kb++) {
            const int p = kb & 1;
            const int k0 = kb * 64;
            __syncthreads();  // stage(kb) landed; prior compute done
            if (kb + 1 < nkb) stage(kb + 1, 1 - p);

            if (k0 <= qr0 + 31) {
                bf16x8 fk[4][2];
#pragma unroll
                for (int ni = 0; ni < 4; ni++) {
                    const int r = ni * 16 + lane15;
#pragma unroll
                    for (int kk = 0; kk < 2; kk++)
                        fk[ni][kk] =
                            *(const bf16x8*)(&Ks[p][r * 64 + (((kk * 4 + quad) ^ (r & 7)) * 8)]);
                }
                f32x4 s[2][4];
#pragma unroll
                for (int mi = 0; mi < 2; mi++)
#pragma unroll
                    for (int ni = 0; ni < 4; ni++) {
                        if (k0 + ni * 16 <= qr0 + mi * 16 + 15) {
                            f32x4 a = zero4;
                            a = MFMA16(fq[mi][0], fk[ni][0], a);
                            a = MFMA16(fq[mi][1], fk[ni][1], a);
                            s[mi][ni] = a;
                        }
                    }
                const bool domask = (k0 + 63 > qr0);
#pragma unroll
                for (int mi = 0; mi < 2; mi++)
#pragma unroll
                    for (int ni = 0; ni < 4; ni++) {
#pragma unroll
                        for (int r = 0; r < 4; r++) {
                            const int prow = mi * 16 + quad * 4 + r;
                            const int r7 = (quad * 4 + r) & 7;
                            const int paddr = prow * 64 +
                                              (((ni * 2 + (lane15 >> 3)) ^ r7) * 8) + (lane15 & 7);
                            float val;
                            if (domask && (k0 + ni * 16 > qr0 + mi * 16 + 15)) {
                                val = 0.f;
                            } else if (domask && (k0 + ni * 16 + 15 > qr0 + mi * 16)) {
                                const int key = k0 + ni * 16 + lane15;
                                const int row = qr0 + prow;
                                float L = (key > row) ? -1e30f : s[mi][ni][r] * c1;
                                val = __builtin_amdgcn_exp2f(L);
                            } else {
                                val = __builtin_amdgcn_exp2f(s[mi][ni][r] * c1);
                            }
                            Ps[wave][paddr] = (bf16)val;
                        }
                    }
                bf16x8 fp[2][2];
#pragma unroll
                for (int mi = 0; mi < 2; mi++) {
                    const int r = mi * 16 + lane15;
#pragma unroll
                    for (int kk = 0; kk < 2; kk++)
                        fp[mi][kk] =
                            *(const bf16x8*)(&Ps[wave][r * 64 + (((kk * 4 + quad) ^ (r & 7)) * 8)]);
                }
                const bool use_kk1 = (k0 + 32 <= qr0 + 31);
#pragma unroll
                for (int ni = 0; ni < 5; ni++) {
                    bf16x8 fv0, fv1;
                    if (ni < 4) {
                        const int r = ni * 16 + lane15;
                        fv0 = *(const bf16x8*)(&Vs[p][r * 64 + ((quad ^ (r & 7)) * 8)]);
                        fv1 = *(const bf16x8*)(&Vs[p][r * 64 + (((4 + quad) ^ (r & 7)) * 8)]);
                    } else {
                        fv0 = *(const bf16x8*)(Ones + lane15 * 64 + quad * 8);
                        fv1 = *(const bf16x8*)(Ones + lane15 * 64 + 32 + quad * 8);
                    }
#pragma unroll
                    for (int mi = 0; mi < 2; mi++) {
                        f32x4* dst = (ni < 4) ? &o[mi][ni] : &lacc[mi];
                        f32x4 a = *dst;
                        a = MFMA16(fp[mi][0], fv0, a);
                        if (use_kk1) a = MFMA16(fp[mi][1], fv1, a);
                        *dst = a;
                    }
                }
            }
        }

#pragma unroll
        for (int mi = 0; mi < 2; mi++)
#pragma unroll
            for (int r = 0; r < 4; r++) {
                float l = __shfl(lacc[mi][r], lane & 48);
                const float inv = 1.f / l;
                const size_t base =
                    ((size_t)(b * Tn + qr0 + mi * 16 + quad * 4 + r)) * Cn + h * 64;
#pragma unroll
                for (int ni = 0; ni < 4; ni++)
                    y[base + ni * 16 + lane15] = (bf16)(o[mi][ni][r] * inv);
            }
        __syncthreads();  // protect K/V/Ps reuse before next half's stage(0)
    }
}

// ---------------------------------------------------------------------------
extern "C" void kernel_launch(void* const* d_in, const int* in_sizes, int n_in,
                              void* d_out, int out_size, void* d_ws, size_t ws_size,
                              hipStream_t stream) {
    const float* x = (const float*)d_in[0];
    const float* Wqkv = (const float*)d_in[1];
    const float* bqkv = (const float*)d_in[2];
    const float* Wproj = (const float*)d_in[3];
    const float* bproj = (const float*)d_in[4];
    const float* ln1g = (const float*)d_in[5];
    const float* ln1b = (const float*)d_in[6];
    const float* ln2g = (const float*)d_in[7];
    const float* ln2b = (const float*)d_in[8];
    const float* W1 = (const float*)d_in[9];
    const float* b1 = (const float*)d_in[10];
    const float* W2 = (const float*)d_in[11];
    const float* b2 = (const float*)d_in[12];
    float* out = (float*)d_out;

    char* ws = (char*)d_ws;
    size_t off = 0;
    auto alloc = [&](size_t bytes) {
        void* p = ws + off;
        off += (bytes + 255) & ~(size_t)255;
        return p;
    };
    bf16* WqkvT = (bf16*)alloc((size_t)3072 * 1024 * 2);
    bf16* WprojT = (bf16*)alloc((size_t)1024 * 1024 * 2);
    bf16* W1T = (bf16*)alloc((size_t)4096 * 1024 * 2);
    bf16* W2T = (bf16*)alloc((size_t)1024 * 4096 * 2);
    bf16* hbuf = (bf16*)alloc((size_t)8192 * 1024 * 2);
    bf16* qkvb = (bf16*)alloc((size_t)8192 * 3072 * 2);
    bf16* ybuf = (bf16*)alloc((size_t)8192 * 1024 * 2);
    bf16* vtb = (bf16*)alloc((size_t)8192 * 1024 * 2);
    bf16* x1b = (bf16*)alloc((size_t)8192 * 1024 * 2);
    bf16* a1 = qkvb;  // reuse qkv(48MB)+y(16MB) region for a1 (64MB); dead by MLP1

    // all weights -> bf16 transposed, single dispatch
    tcast_all<<<12288, 256, 0, stream>>>(Wqkv, Wproj, W1, W2, WqkvT, WprojT, W1T, W2T);

    // LN1 -> h
    ln_row<float><<<8192, 256, 0, stream>>>(x, ln1g, ln1b, hbuf);
    // qkv = h @ Wqkv + bqkv  (bf16)   TM=128, TN=256, BK=64
    gemm_bt<128, 256, 64, false, false, true, float><<<dim3(64, 12), 256, 0, stream>>>(
        hbuf, WqkvT, bqkv, (const float*)nullptr, qkvb, 8192, 3072, 1024);
    // V -> Vt [B,H,64,T]
    vtrans<<<dim3(Bn * Hn, Tn / 64), 256, 0, stream>>>(qkvb, vtb);
    // attention -> y (bf16); paired causal tiles, uniform work
    attn<<<dim3(Bn * Hn, 4), 256, 0, stream>>>(qkvb, vtb, ybuf);
    // x1 = x + y @ Wproj + bproj  (bf16)   TM=TN=128, BK=128
    gemm_bt<128, 128, 128, false, true, true, float><<<dim3(64, 8), 256, 0, stream>>>(
        ybuf, WprojT, bproj, x, x1b, 8192, 1024, 1024);
    // LN2 -> h
    ln_row<bf16><<<8192, 256, 0, stream>>>(x1b, ln2g, ln2b, hbuf);
    // a1 = relu(h @ W1 + b1)  (bf16)   TM=128, TN=256, BK=64
    gemm_bt<128, 256, 64, true, false, true, float><<<dim3(64, 16), 256, 0, stream>>>(
        hbuf, W1T, b1, (const float*)nullptr, a1, 8192, 4096, 1024);
    // out = x1 + a1 @ W2 + b2  (fp32)   TM=TN=128, BK=128
    gemm_bt<128, 128, 128, false, true, false, bf16><<<dim3(64, 8), 256, 0, stream>>>(
        a1, W2T, b2, x1b, out, 8192, 1024, 4096);
}